// Round 7
// baseline (633.145 us; speedup 1.0000x reference)
//
#include <hip/hip_runtime.h>
#include <hip/hip_bf16.h>

#define P     10
#define NTOK  59
#define HEADS 12
#define NWTOK 49

#define AW_OFF 38535168   // frozen: verified by 5 passing rounds
#define PO_OFF 124096512  // frozen: verified by 5 passing rounds

typedef __attribute__((ext_vector_type(8))) short short8;
typedef __attribute__((ext_vector_type(8))) unsigned short ushort8;
typedef __attribute__((ext_vector_type(4))) float floatx4;
typedef float f4u __attribute__((ext_vector_type(4), aligned(4)));
typedef unsigned int uint_g __attribute__((address_space(1)));
typedef unsigned int uint_l __attribute__((address_space(3)));

__device__ __forceinline__ unsigned short f2b(float f) {
  unsigned u = __builtin_bit_cast(unsigned, f);
  u += 0x7fffu + ((u >> 16) & 1u);
  return (unsigned short)(u >> 16);
}

__device__ __forceinline__ void gll16(const void* g, void* l) {
  __builtin_amdgcn_global_load_lds((const uint_g*)g, (uint_l*)l, 16, 0, 0);
}

// ---------------------------------------------------------------------------
// convert f32 -> bf16 flat (grid sized exactly: n/8/256 blocks)
// ---------------------------------------------------------------------------
__global__ __launch_bounds__(256) void convert_w_kernel(
    const float* __restrict__ w, unsigned short* __restrict__ wb) {
  const int i = (blockIdx.x * 256 + threadIdx.x) * 8;
  const float4 a = *(const float4*)(w + i);
  const float4 b = *(const float4*)(w + i + 4);
  ushort8 o;
  o[0] = f2b(a.x); o[1] = f2b(a.y); o[2] = f2b(a.z); o[3] = f2b(a.w);
  o[4] = f2b(b.x); o[5] = f2b(b.y); o[6] = f2b(b.z); o[7] = f2b(b.w);
  *(ushort8*)(wb + i) = o;
}

// ---------------------------------------------------------------------------
// combo[wnd][h][ti][tj] = bias_table[relidx(ti,tj)][h] + mask[wnd][ti][tj]
// ---------------------------------------------------------------------------
__global__ __launch_bounds__(256) void combo_kernel(
    const float* __restrict__ mask, const float* __restrict__ bias_table,
    float* __restrict__ combo) {
  const int bid = blockIdx.x;          // wnd*12 + h
  const int h = bid % HEADS, wnd = bid / HEADS;
  for (int e = threadIdx.x; e < 2401; e += 256) {
    const int ti = e / 49, tj = e - (e / 49) * 49;
    const int ai = ti / 7, aj = ti - ai * 7;
    const int bi = tj / 7, bj = tj - bi * 7;
    const int ridx = (ai - bi + 6) * 13 + (aj - bj + 6);
    combo[(size_t)bid * 2401 + e] =
        bias_table[ridx * HEADS + h] + mask[(size_t)wnd * 2401 + e];
  }
}

// ---------------------------------------------------------------------------
// FUSED: per-window QKV GEMM (all heads in registers) + attention.
// 512 threads (8 waves), 1 block/CU. LDS 87040 B, phase-aliased.
// ---------------------------------------------------------------------------
__global__ __launch_bounds__(512, 2) void fused_qkv_attn_kernel(
    const float* __restrict__ x, const float* __restrict__ spa,
    const unsigned short* __restrict__ wqb, const float* __restrict__ b_qkv,
    const float* __restrict__ combo, float* __restrict__ aw_out,
    unsigned short* __restrict__ attn_bf) {
  __shared__ char lds[87040];
  // phase 1:
  unsigned short* xs   = (unsigned short*)lds;             // [64][392] bf16
  unsigned short* wstA = (unsigned short*)(lds + 50176);   // [128][64] swz
  unsigned short* wstB = (unsigned short*)(lds + 66560);   // [128][64] swz
  // phase 2 (aliases phase-1 regions, sequenced by barriers):
  unsigned short* q_l  = (unsigned short*)lds;             // [64][200]
  unsigned short* k_l  = (unsigned short*)(lds + 25600);   // [64][200]
  unsigned short* vt   = (unsigned short*)(lds + 51200);   // [6][32][72] V^T
  unsigned short* obuf = (unsigned short*)(lds + 78848);   // 8 x [16][32]

  const int b = blockIdx.x;
  const int t = threadIdx.x;
  const int w = t >> 6, lane = t & 63, lr = lane & 15, lg = lane >> 4;
  const int rB = w * 16 + lr;  // B-tile row this lane reads in phase 1

  // ---- stage xc (f32 -> bf16), rows 59..63 zero ----
#pragma unroll
  for (int ci = 0; ci < 6; ++ci) {
    const int e = ci * 4096 + t * 8;
    const int r = e / 384, c = e - r * 384;
    ushort8 o;
    if (r < NTOK) {
      const float* src = (r < P)
          ? spa + ((size_t)((b >> 6) * P + r)) * 384 + c
          : x + ((size_t)(b * NWTOK + r - P)) * 384 + c;
      const float4 v0 = ((const float4*)src)[0];
      const float4 v1 = ((const float4*)src)[1];
      o[0] = f2b(v0.x); o[1] = f2b(v0.y); o[2] = f2b(v0.z); o[3] = f2b(v0.w);
      o[4] = f2b(v1.x); o[5] = f2b(v1.y); o[6] = f2b(v1.z); o[7] = f2b(v1.w);
    } else {
      o = (ushort8)0;
    }
    *(ushort8*)(xs + r * 392 + c) = o;
  }

  // ---- stage W tile s=0 (rows 0..127, k 0..63) ----
#pragma unroll
  for (int i = 0; i < 2; ++i) {
    const int g = w * 2 + i;
    const int r = g * 8 + (lane >> 3);
    const int c = (lane & 7) ^ (r & 7);
    gll16(wqb + (size_t)r * 384 + c * 8, wstA + g * 512);
  }
  __syncthreads();

  floatx4 acc[9][4];
#pragma unroll
  for (int n9 = 0; n9 < 9; ++n9)
#pragma unroll
    for (int mt = 0; mt < 4; ++mt) acc[n9][mt] = (floatx4)0.f;

  short8 af[2][4];
  // ---- 54-step K-outer / N-inner sweep, double-buffered W ----
#pragma unroll
  for (int s = 0; s < 54; ++s) {
    const int kz = s / 9, nt9 = s % 9;
    unsigned short* cur = (s & 1) ? wstB : wstA;
    unsigned short* nxt = (s & 1) ? wstA : wstB;
    if (nt9 == 0) {
#pragma unroll
      for (int kk = 0; kk < 2; ++kk)
#pragma unroll
        for (int mt = 0; mt < 4; ++mt)
          af[kk][mt] = *(const short8*)(xs + (mt * 16 + lr) * 392 + kz * 64 +
                                        kk * 32 + lg * 8);
    }
    if (s < 53) {
      const int s1 = s + 1, kz1 = s1 / 9, nt1 = s1 % 9;
#pragma unroll
      for (int i = 0; i < 2; ++i) {
        const int g = w * 2 + i;
        const int r = g * 8 + (lane >> 3);
        const int c = (lane & 7) ^ (r & 7);
        gll16(wqb + (size_t)(nt1 * 128 + r) * 384 + kz1 * 64 + c * 8,
              nxt + g * 512);
      }
    }
#pragma unroll
    for (int kk = 0; kk < 2; ++kk) {
      const short8 bf =
          *(const short8*)(cur + rB * 64 + (((kk * 4 + lg) ^ (rB & 7)) * 8));
#pragma unroll
      for (int mt = 0; mt < 4; ++mt)
        acc[nt9][mt] = __builtin_amdgcn_mfma_f32_16x16x32_bf16(
            af[kk][mt], bf, acc[nt9][mt], 0, 0, 0);
    }
    __syncthreads();
  }

  // ---- phase 2: two rounds of 6 heads ----
  float bias9[9];
#pragma unroll
  for (int i = 0; i < 9; ++i) bias9[i] = b_qkv[i * 128 + w * 16 + lr];
  const int d_sc = (w & 1) * 16 + lr;
  const int hw = w >> 1;
  const float scale = 0.17677669529663687f;

#pragma unroll
  for (int rnd = 0; rnd < 2; ++rnd) {
    // scatter this round's heads (q_l / k_l / vt); frag (nt9,w) -> head h
#pragma unroll
    for (int nt9 = 0; nt9 < 9; ++nt9) {
      const int sec = nt9 / 3;
      const int h = (nt9 % 3) * 4 + hw;          // wave-uniform
      if ((h >= 6 ? 1 : 0) == rnd) {
        const int hl = h - rnd * 6;
#pragma unroll
        for (int mt = 0; mt < 4; ++mt) {
          if (sec == 2) {
#pragma unroll
            for (int pp = 0; pp < 2; ++pp) {
              const int m = mt * 16 + lg * 4 + pp * 2;
              const unsigned u =
                  (unsigned)f2b(acc[nt9][mt][pp * 2] + bias9[nt9]) |
                  ((unsigned)f2b(acc[nt9][mt][pp * 2 + 1] + bias9[nt9]) << 16);
              *(unsigned*)(vt + hl * 2304 + d_sc * 72 + m) = u;
            }
          } else {
            unsigned short* dst = (sec == 0) ? q_l : k_l;
#pragma unroll
            for (int reg = 0; reg < 4; ++reg) {
              const int m = mt * 16 + lg * 4 + reg;
              dst[m * 200 + hl * 32 + d_sc] = f2b(acc[nt9][mt][reg] + bias9[nt9]);
            }
          }
        }
      }
    }
    __syncthreads();

    // 24 tasks = 6 heads x 4 q-groups; 3 per wave
#pragma unroll
    for (int i = 0; i < 3; ++i) {
      const int tau = w * 3 + i;
      const int hl = tau >> 2, qw = tau & 3;
      const int hg = rnd * 6 + hl;
      const int q = qw * 16 + lr;

      // S^T trick: lane holds S[q][k=nt*16+lg*4+reg]
      const short8 qa = *(const short8*)(q_l + q * 200 + hl * 32 + lg * 8);
      floatx4 sacc[4];
#pragma unroll
      for (int nt = 0; nt < 4; ++nt) {
        const short8 kb =
            *(const short8*)(k_l + (nt * 16 + lr) * 200 + hl * 32 + lg * 8);
        sacc[nt] = __builtin_amdgcn_mfma_f32_16x16x32_bf16(kb, qa, (floatx4)0.f,
                                                           0, 0, 0);
      }
      // raw S from registers
      if (q < NTOK) {
        float* rowp = aw_out + ((size_t)(b * HEADS + hg)) * 3481 + q * 59;
#pragma unroll
        for (int nt = 0; nt < 3; ++nt)
          *(f4u*)(rowp + nt * 16 + lg * 4) = __builtin_bit_cast(f4u, sacc[nt]);
        if (lg < 2) {
          *(f4u*)(rowp + 48 + lg * 4) = __builtin_bit_cast(f4u, sacc[3]);
        } else if (lg == 2) {
          rowp[56] = sacc[3][0]; rowp[57] = sacc[3][1]; rowp[58] = sacc[3][2];
        }
      }

      // in-register softmax
      const float* comb = combo + (size_t)((b & 63) * HEADS + hg) * 2401;
      float ev[4][4];
      float mx = -3.0e38f;
#pragma unroll
      for (int nt = 0; nt < 4; ++nt)
#pragma unroll
        for (int reg = 0; reg < 4; ++reg) {
          const int kk2 = nt * 16 + lg * 4 + reg;
          float v = -3.0e38f;
          if (q < NTOK && kk2 < NTOK) {
            const float cb =
                (q >= P && kk2 >= P) ? comb[(q - P) * 49 + (kk2 - P)] : 0.f;
            v = fmaf(sacc[nt][reg], scale, cb);
          }
          ev[nt][reg] = v;
          mx = fmaxf(mx, v);
        }
      mx = fmaxf(mx, __shfl_xor(mx, 16));
      mx = fmaxf(mx, __shfl_xor(mx, 32));
      float sm = 0.f;
#pragma unroll
      for (int nt = 0; nt < 4; ++nt)
#pragma unroll
        for (int reg = 0; reg < 4; ++reg) {
          const float e = __expf(ev[nt][reg] - mx);
          ev[nt][reg] = e;
          sm += e;
        }
      sm += __shfl_xor(sm, 16);
      sm += __shfl_xor(sm, 32);
      const float inv = 1.0f / sm;

      // pack P to bf16 pairs: pk[nt][pp] = P[q][nt*16+lg*4+2pp .. +1]
      unsigned pk[4][2];
#pragma unroll
      for (int nt = 0; nt < 4; ++nt)
#pragma unroll
        for (int pp = 0; pp < 2; ++pp)
          pk[nt][pp] = (unsigned)f2b(ev[nt][2 * pp] * inv) |
                       ((unsigned)f2b(ev[nt][2 * pp + 1] * inv) << 16);

      // redistribute to MFMA A-layout (k = kk*32+lg*8+j) via shfl, then PV
      floatx4 oacc[2];
      oacc[0] = (floatx4)0.f; oacc[1] = (floatx4)0.f;
#pragma unroll
      for (int kk = 0; kk < 2; ++kk) {
        unsigned W4[4];
#pragma unroll
        for (int jp = 0; jp < 4; ++jp) {
          const int srcl = lr + 16 * (2 * (lg & 1) + (jp >> 1));
          const int lo = __shfl((int)pk[2 * kk][jp & 1], srcl);
          const int hi = __shfl((int)pk[2 * kk + 1][jp & 1], srcl);
          W4[jp] = (lg >> 1) ? (unsigned)hi : (unsigned)lo;
        }
        uint4 wu; wu.x = W4[0]; wu.y = W4[1]; wu.z = W4[2]; wu.w = W4[3];
        const short8 pa = __builtin_bit_cast(short8, wu);
#pragma unroll
        for (int nt = 0; nt < 2; ++nt) {
          const short8 vb = *(const short8*)(vt + hl * 2304 +
                                             (nt * 16 + lr) * 72 + kk * 32 +
                                             lg * 8);
          oacc[nt] =
              __builtin_amdgcn_mfma_f32_16x16x32_bf16(pa, vb, oacc[nt], 0, 0, 0);
        }
      }

      // repack O rows in own-wave slice, 16B/lane store
      unsigned short* wb = obuf + w * 512;
#pragma unroll
      for (int nt = 0; nt < 2; ++nt)
#pragma unroll
        for (int reg = 0; reg < 4; ++reg)
          wb[(lg * 4 + reg) * 32 + nt * 16 + lr] = f2b(oacc[nt][reg]);
      const int rr = lane >> 2, cc = (lane & 3) * 8;
      const int qg = qw * 16 + rr;
      if (qg < NTOK) {
        const ushort8 ov = *(const ushort8*)(wb + rr * 32 + cc);
        *(ushort8*)(attn_bf + ((size_t)(b * NTOK + qg)) * 384 + hg * 32 + cc) =
            ov;
      }
    }
    __syncthreads();
  }
}

// ---------------------------------------------------------------------------
// proj GEMM: [120832][384] = attn_bf @ wproj_bf^T (+bias), f32 routed out.
// (unchanged, proven)
// ---------------------------------------------------------------------------
__global__ __launch_bounds__(256) void gemm_proj_kernel(
    const unsigned short* __restrict__ A, const unsigned short* __restrict__ Bw,
    const float* __restrict__ b_proj, float* __restrict__ x_out,
    float* __restrict__ pbuf) {
  __shared__ unsigned short Asw[8192];
  __shared__ unsigned short Bsw[8192];
  const int t = threadIdx.x;
  const int w = t >> 6, lane = t & 63;
  const int lr = lane & 15, lg = lane >> 4;
  const int w0 = w >> 1, w1 = w & 1;
  const size_t m0 = (size_t)blockIdx.y * 128;
  const int n0 = blockIdx.x * 128;
  const int srow = lane >> 3, cpos = lane & 7;

  floatx4 acc[4][4];
#pragma unroll
  for (int mr = 0; mr < 4; ++mr)
#pragma unroll
    for (int nc = 0; nc < 4; ++nc) acc[mr][nc] = (floatx4)0.f;

  for (int k0 = 0; k0 < 384; k0 += 64) {
#pragma unroll
    for (int i = 0; i < 4; ++i) {
      const int r = (w * 4 + i) * 8 + srow;
      const int c = cpos ^ (r & 7);
      gll16(A + (m0 + r) * 384 + k0 + c * 8, Asw + (w * 4 + i) * 512);
      gll16(Bw + (size_t)(n0 + r) * 384 + k0 + c * 8, Bsw + (w * 4 + i) * 512);
    }
    __syncthreads();
#pragma unroll
    for (int kh = 0; kh < 2; ++kh) {
      short8 af[4], bf[4];
#pragma unroll
      for (int mr = 0; mr < 4; ++mr) {
        const int r = w0 * 64 + mr * 16 + lr;
        af[mr] = *(const short8*)(Asw + r * 64 + (((kh * 4 + lg) ^ (r & 7)) * 8));
      }
#pragma unroll
      for (int nc = 0; nc < 4; ++nc) {
        const int r = w1 * 64 + nc * 16 + lr;
        bf[nc] = *(const short8*)(Bsw + r * 64 + (((kh * 4 + lg) ^ (r & 7)) * 8));
      }
#pragma unroll
      for (int mr = 0; mr < 4; ++mr)
#pragma unroll
        for (int nc = 0; nc < 4; ++nc)
          acc[mr][nc] = __builtin_amdgcn_mfma_f32_16x16x32_bf16(
              af[mr], bf[nc], acc[mr][nc], 0, 0, 0);
    }
    __syncthreads();
  }

  float bias[4]; int nn[4];
#pragma unroll
  for (int nc = 0; nc < 4; ++nc) {
    nn[nc] = n0 + w1 * 64 + nc * 16 + lr;
    bias[nc] = b_proj[nn[nc]];
  }
#pragma unroll
  for (int mr = 0; mr < 4; ++mr)
#pragma unroll
    for (int reg = 0; reg < 4; ++reg) {
      const int m = (int)m0 + w0 * 64 + mr * 16 + lg * 4 + reg;
      const int bb = m / 59, tok = m - bb * 59;
      float* dst = (tok >= P)
          ? x_out + (size_t)(bb * NWTOK + tok - P) * 384
          : pbuf + (size_t)(bb * P + tok) * 384;
#pragma unroll
      for (int nc = 0; nc < 4; ++nc)
        dst[nn[nc]] = acc[mr][nc][reg] + bias[nc];
    }
}

// ---------------------------------------------------------------------------
// prompts_out = mean over 64 windows
// ---------------------------------------------------------------------------
__global__ __launch_bounds__(256) void reduce_prompts_kernel(
    const float* __restrict__ pbuf, float* __restrict__ po) {
  const int o = blockIdx.x * 256 + threadIdx.x;  // < 32*10*384
  const int b0 = o / 3840;
  const int rem = o - b0 * 3840;
  const float* base = pbuf + (size_t)b0 * 64 * 3840 + rem;
  float s = 0.f;
#pragma unroll 8
  for (int w = 0; w < 64; ++w) s += base[(size_t)w * 3840];
  po[o] = s * (1.f / 64.f);
}

extern "C" void kernel_launch(void* const* d_in, const int* in_sizes, int n_in,
                              void* d_out, int out_size, void* d_ws, size_t ws_size,
                              hipStream_t stream) {
  const float* x          = (const float*)d_in[0];
  const float* spa        = (const float*)d_in[1];
  const float* mask       = (const float*)d_in[2];
  const float* bias_table = (const float*)d_in[3];
  const float* w_qkv      = (const float*)d_in[4];
  const float* b_qkv      = (const float*)d_in[5];
  const float* w_proj     = (const float*)d_in[6];
  const float* b_proj     = (const float*)d_in[7];
  float* out = (float*)d_out;

  // ws layout (bytes):
  // [0, 92798976)            attn_bf (bf16 120832x384)
  // [92798976, 93683712)     wqkv_bf (bf16 1152x384)
  // [93683712, 93978624)     wproj_bf (bf16 384x384)
  // [93978624, 125435904)    pbuf  (f32 2048*10*384)
  // [125435904, 132811776)   combo (f32 64*12*49*49)
  unsigned short* attn_bf  = (unsigned short*)d_ws;
  unsigned short* wqkv_bf  = (unsigned short*)((char*)d_ws + 92798976ULL);
  unsigned short* wproj_bf = (unsigned short*)((char*)d_ws + 93683712ULL);
  float*          pbuf     = (float*)((char*)d_ws + 93978624ULL);
  float*          combo    = (float*)((char*)d_ws + 125435904ULL);

  convert_w_kernel<<<216, 256, 0, stream>>>(w_qkv, wqkv_bf);
  convert_w_kernel<<<72, 256, 0, stream>>>(w_proj, wproj_bf);
  combo_kernel<<<768, 256, 0, stream>>>(mask, bias_table, combo);
  fused_qkv_attn_kernel<<<2048, 512, 0, stream>>>(
      x, spa, wqkv_bf, b_qkv, combo, out + AW_OFF, attn_bf);
  gemm_proj_kernel<<<dim3(3, 944), 256, 0, stream>>>(attn_bf, wproj_bf, b_proj,
                                                     out, pbuf);
  reduce_prompts_kernel<<<480, 256, 0, stream>>>(pbuf, out + PO_OFF);
}

// Round 8
// 596.431 us; speedup vs baseline: 1.0616x; 1.0616x over previous
//
#include <hip/hip_runtime.h>
#include <hip/hip_bf16.h>

#define P     10
#define NTOK  59
#define HEADS 12
#define NWTOK 49

#define AW_OFF 38535168   // frozen: verified by 6 passing rounds
#define PO_OFF 124096512  // frozen: verified by 6 passing rounds

typedef __attribute__((ext_vector_type(8))) short short8;
typedef __attribute__((ext_vector_type(8))) unsigned short ushort8;
typedef __attribute__((ext_vector_type(4))) float floatx4;
typedef float f4u __attribute__((ext_vector_type(4), aligned(4)));
typedef unsigned int uint_g __attribute__((address_space(1)));
typedef unsigned int uint_l __attribute__((address_space(3)));

__device__ __forceinline__ unsigned short f2b(float f) {
  unsigned u = __builtin_bit_cast(unsigned, f);
  u += 0x7fffu + ((u >> 16) & 1u);
  return (unsigned short)(u >> 16);
}

__device__ __forceinline__ void gll16(const void* g, void* l) {
  __builtin_amdgcn_global_load_lds((const uint_g*)g, (uint_l*)l, 16, 0, 0);
}

// bijective XCD-aware block swizzle (m204 form)
__device__ __forceinline__ int xcd_swz(int bid, int nwg) {
  const int q = nwg >> 3, r = nwg & 7;
  const int xcd = bid & 7, ord = bid >> 3;
  return (xcd < r ? xcd * (q + 1) : r * (q + 1) + (xcd - r) * q) + ord;
}

// ---------------------------------------------------------------------------
// convert f32 -> bf16 flat (grid sized exactly: n/8/256 blocks)
// ---------------------------------------------------------------------------
__global__ __launch_bounds__(256) void convert_w_kernel(
    const float* __restrict__ w, unsigned short* __restrict__ wb) {
  const int i = (blockIdx.x * 256 + threadIdx.x) * 8;
  const float4 a = *(const float4*)(w + i);
  const float4 b = *(const float4*)(w + i + 4);
  ushort8 o;
  o[0] = f2b(a.x); o[1] = f2b(a.y); o[2] = f2b(a.z); o[3] = f2b(a.w);
  o[4] = f2b(b.x); o[5] = f2b(b.y); o[6] = f2b(b.z); o[7] = f2b(b.w);
  *(ushort8*)(wb + i) = o;
}

// ---------------------------------------------------------------------------
// combo[wnd][h][64][64]: padded with zeros outside the 49x49 valid region.
// combo[ti][tj] = bias_table[relidx][h] + mask[wnd][ti-P][tj-P]
// ---------------------------------------------------------------------------
__global__ __launch_bounds__(256) void combo_kernel(
    const float* __restrict__ mask, const float* __restrict__ bias_table,
    float* __restrict__ combo) {
  const int bid = blockIdx.x;          // wnd*12 + h
  const int h = bid % HEADS, wnd = bid / HEADS;
#pragma unroll
  for (int e0 = 0; e0 < 4096; e0 += 256) {
    const int e = e0 + threadIdx.x;
    const int ti = e >> 6, tj = e & 63;
    float v = 0.f;
    if (ti >= P && ti < NTOK && tj >= P && tj < NTOK) {
      const int a = ti - P, c = tj - P;
      const int ai = a / 7, aj = a - ai * 7;
      const int bi = c / 7, bj = c - bi * 7;
      const int ridx = (ai - bi + 6) * 13 + (aj - bj + 6);
      v = bias_table[ridx * HEADS + h] + mask[((size_t)wnd * 49 + a) * 49 + c];
    }
    combo[((size_t)bid << 12) + e] = v;
  }
}

// ---------------------------------------------------------------------------
// QKV GEMM: x-rows (784 row-blocks) + prompt rows (3 row-blocks, 320 valid).
// BM=BN=128, BK=64, 4 waves; global_load_lds w/ XOR-swizzled source.
// NEW: row-contiguous output qkx[bb][sec][tok49][384], qkp[b0][sec][tok10][384]
//      via per-wave LDS repack -> 8x ushort8 (128B) coalesced stores per lane.
// ---------------------------------------------------------------------------
__global__ __launch_bounds__(256) void gemm_qkv_kernel(
    const unsigned short* __restrict__ xb, const unsigned short* __restrict__ xp,
    const unsigned short* __restrict__ Bw, const float* __restrict__ b_qkv,
    unsigned short* __restrict__ qkx, unsigned short* __restrict__ qkp) {
  __shared__ unsigned short sbuf[18432];   // 36864 B: Asw|Bsw, reused as repack
  unsigned short* Asw = sbuf;
  unsigned short* Bsw = sbuf + 8192;
  const int t = threadIdx.x;
  const int w = t >> 6, lane = t & 63;
  const int lr = lane & 15, lg = lane >> 4;
  const int w0 = w >> 1, w1 = w & 1;
  // XCD swizzle: 9 consecutive wg (same A row-tile) land on one XCD
  const int wg = xcd_swz(blockIdx.x, 9 * 787);
  const int cb = wg % 9;          // column block 0..8
  const int my = wg / 9;          // row block 0..786
  const bool isP = my >= 784;
  const int n0 = cb * 128;
  const int srow = lane >> 3, cpos = lane & 7;

  floatx4 acc[4][4];
#pragma unroll
  for (int mr = 0; mr < 4; ++mr)
#pragma unroll
    for (int nc = 0; nc < 4; ++nc) acc[mr][nc] = (floatx4)0.f;

  for (int k0 = 0; k0 < 384; k0 += 64) {
#pragma unroll
    for (int i = 0; i < 4; ++i) {
      const int r = (w * 4 + i) * 8 + srow;
      const int c = cpos ^ (r & 7);
      const unsigned short* asrc;
      if (!isP) {
        asrc = xb + (size_t)(my * 128 + r) * 384 + k0 + c * 8;
      } else {
        int mp = (my - 784) * 128 + r;
        if (mp > 319) mp = 319;
        asrc = xp + (size_t)mp * 384 + k0 + c * 8;
      }
      gll16(asrc, Asw + (w * 4 + i) * 512);
      gll16(Bw + (size_t)(n0 + r) * 384 + k0 + c * 8, Bsw + (w * 4 + i) * 512);
    }
    __syncthreads();
#pragma unroll
    for (int kh = 0; kh < 2; ++kh) {
      short8 af[4], bf[4];
#pragma unroll
      for (int mr = 0; mr < 4; ++mr) {
        const int r = w0 * 64 + mr * 16 + lr;
        af[mr] = *(const short8*)(Asw + r * 64 + (((kh * 4 + lg) ^ (r & 7)) * 8));
      }
#pragma unroll
      for (int nc = 0; nc < 4; ++nc) {
        const int r = w1 * 64 + nc * 16 + lr;
        bf[nc] = *(const short8*)(Bsw + r * 64 + (((kh * 4 + lg) ^ (r & 7)) * 8));
      }
#pragma unroll
      for (int mr = 0; mr < 4; ++mr)
#pragma unroll
        for (int nc = 0; nc < 4; ++nc)
          acc[mr][nc] = __builtin_amdgcn_mfma_f32_16x16x32_bf16(
              af[mr], bf[nc], acc[mr][nc], 0, 0, 0);
    }
    __syncthreads();
  }

  // ---- epilogue: +bias, per-wave 64x64 LDS repack, 128B/lane stores ----
  const int sec = cb / 3;
  const int nis = (cb - sec * 3) * 128;   // col offset within sec
  float bias[4];
#pragma unroll
  for (int nc = 0; nc < 4; ++nc)
    bias[nc] = b_qkv[n0 + w1 * 64 + nc * 16 + lr];

  unsigned short* rp = sbuf + w * 4608;   // own wave: [64][72]
#pragma unroll
  for (int mr = 0; mr < 4; ++mr)
#pragma unroll
    for (int nc = 0; nc < 4; ++nc)
#pragma unroll
      for (int reg = 0; reg < 4; ++reg)
        rp[(mr * 16 + lg * 4 + reg) * 72 + nc * 16 + lr] =
            f2b(acc[mr][nc][reg] + bias[nc]);
  __syncthreads();

  const int rr = lane;  // local row 0..63 of this wave's quadrant
  unsigned short* dst = nullptr;
  if (!isP) {
    const int m = my * 128 + w0 * 64 + rr;
    const int bb = m / 49, tok = m - bb * 49;
    dst = qkx + ((size_t)(bb * 3 + sec) * 49 + tok) * 384 + nis + w1 * 64;
  } else {
    const int mp = (my - 784) * 128 + w0 * 64 + rr;
    if (mp < 320) {
      const int b0 = mp / 10, ptok = mp - b0 * 10;
      dst = qkp + ((size_t)(b0 * 3 + sec) * 10 + ptok) * 384 + nis + w1 * 64;
    }
  }
  if (dst) {
#pragma unroll
    for (int u = 0; u < 8; ++u)
      *(ushort8*)(dst + u * 8) = *(const ushort8*)(rp + rr * 72 + u * 8);
  }
}

// ---------------------------------------------------------------------------
// attention: per (b,h), 4 waves. Swapped QK^T -> in-reg softmax,
// direct-reg aw stores, float4 combo loads, packed attn_bf stores.
// ---------------------------------------------------------------------------
__global__ __launch_bounds__(256) void attn_kernel(
    const unsigned short* __restrict__ qkx, const unsigned short* __restrict__ qkp,
    const float* __restrict__ combo, float* __restrict__ aw_out,
    unsigned short* __restrict__ attn_bf) {
  __shared__ char lds[14976];
  unsigned short* qs = (unsigned short*)(lds);          // [64][40]
  unsigned short* ks = (unsigned short*)(lds + 5120);   // [64][40]
  unsigned short* vt = (unsigned short*)(lds + 10240);  // [32][74] (V^T)
  unsigned short* Pm = (unsigned short*)(lds);          // [64][72], alias qs/ks

  const int blk = blockIdx.x;
  const int b = blk / HEADS, h = blk - b * HEADS;
  const int t = threadIdx.x;
  const int w = t >> 6, lane = t & 63, lr = lane & 15, lg = lane >> 4;

  // ---- stage q/k/v (row-contiguous layouts) ----
  if (t < 236) {
    const int row = t >> 2, dc = (t & 3) * 8;
    ushort8 q8, k8, v8;
    if (row < P) {
      const unsigned short* pb =
          qkp + ((size_t)((b >> 6) * 3) * 10 + row) * 384 + h * 32 + dc;
      q8 = *(const ushort8*)(pb);
      k8 = *(const ushort8*)(pb + 10 * 384);
      v8 = *(const ushort8*)(pb + 20 * 384);
    } else {
      const unsigned short* xbp =
          qkx + ((size_t)(b * 3) * 49 + (row - P)) * 384 + h * 32 + dc;
      q8 = *(const ushort8*)(xbp);
      k8 = *(const ushort8*)(xbp + 49 * 384);
      v8 = *(const ushort8*)(xbp + 98 * 384);
    }
    *(ushort8*)(qs + row * 40 + dc) = q8;
    *(ushort8*)(ks + row * 40 + dc) = k8;
#pragma unroll
    for (int j = 0; j < 8; ++j) vt[(dc + j) * 74 + row] = v8[j];
  } else {
    const int e = t - 236;  // zero vt token cols 59..63
#pragma unroll
    for (int jj = 0; jj < 8; ++jj) {
      const int f = e * 8 + jj;  // 0..159
      vt[(f / 5) * 74 + 59 + (f % 5)] = 0;
    }
  }
  __syncthreads();

  // ---- S^T trick: mfma(K,Q) -> lane holds S[q][kk], q=w*16+lr ----
  const int q = w * 16 + lr;
  const short8 qa = *(const short8*)(qs + q * 40 + lg * 8);
  floatx4 sacc[4];
#pragma unroll
  for (int nt = 0; nt < 4; ++nt) {
    const short8 kb = *(const short8*)(ks + (nt * 16 + lr) * 40 + lg * 8);
    sacc[nt] = __builtin_amdgcn_mfma_f32_16x16x32_bf16(kb, qa, (floatx4)0.f, 0, 0, 0);
  }

  // ---- raw S straight from registers ----
  if (q < NTOK) {
    float* rowp = aw_out + (size_t)blk * 3481 + q * 59;
#pragma unroll
    for (int nt = 0; nt < 3; ++nt)
      *(f4u*)(rowp + nt * 16 + lg * 4) = __builtin_bit_cast(f4u, sacc[nt]);
    if (lg < 2) {
      *(f4u*)(rowp + 48 + lg * 4) = __builtin_bit_cast(f4u, sacc[3]);
    } else if (lg == 2) {
      rowp[56] = sacc[3][0];
      rowp[57] = sacc[3][1];
      rowp[58] = sacc[3][2];
    }
  }

  // ---- in-register softmax (float4 combo loads, branchless mask) ----
  const float scale = 0.17677669529663687f;
  const float* comb = combo + (((size_t)((b & 63) * HEADS + h)) << 12) + q * 64;
  float ev[4][4];
  float mx = -3.0e38f;
#pragma unroll
  for (int nt = 0; nt < 4; ++nt) {
    const float4 c4 = *(const float4*)(comb + nt * 16 + lg * 4);
    const float cc[4] = {c4.x, c4.y, c4.z, c4.w};
#pragma unroll
    for (int reg = 0; reg < 4; ++reg) {
      const int kk2 = nt * 16 + lg * 4 + reg;
      const float v = (q < NTOK && kk2 < NTOK)
                          ? fmaf(sacc[nt][reg], scale, cc[reg])
                          : -3.0e38f;
      ev[nt][reg] = v;
      mx = fmaxf(mx, v);
    }
  }
  mx = fmaxf(mx, __shfl_xor(mx, 16));
  mx = fmaxf(mx, __shfl_xor(mx, 32));
  float sm = 0.f;
#pragma unroll
  for (int nt = 0; nt < 4; ++nt)
#pragma unroll
    for (int reg = 0; reg < 4; ++reg) {
      const float e = __expf(ev[nt][reg] - mx);
      ev[nt][reg] = e;
      sm += e;
    }
  sm += __shfl_xor(sm, 16);
  sm += __shfl_xor(sm, 32);
  const float inv = 1.0f / sm;

  // Pm aliases qs/ks: wait until all waves finished their kb reads
  __syncthreads();
#pragma unroll
  for (int nt = 0; nt < 4; ++nt) {
    uint2 uu;
    uu.x = (unsigned)f2b(ev[nt][0] * inv) | ((unsigned)f2b(ev[nt][1] * inv) << 16);
    uu.y = (unsigned)f2b(ev[nt][2] * inv) | ((unsigned)f2b(ev[nt][3] * inv) << 16);
    *(uint2*)(Pm + q * 72 + nt * 16 + lg * 4) = uu;
  }

  // ---- O = P @ V (wave-local deps; LDS ops in-order per wave) ----
  floatx4 oacc[2];
  oacc[0] = (floatx4)0.f; oacc[1] = (floatx4)0.f;
#pragma unroll
  for (int kk = 0; kk < 2; ++kk) {
    const short8 pa = *(const short8*)(Pm + (w * 16 + lr) * 72 + kk * 32 + lg * 8);
#pragma unroll
    for (int nt = 0; nt < 2; ++nt) {
      const short8 vb = *(const short8*)(vt + (nt * 16 + lr) * 74 + kk * 32 + lg * 8);
      oacc[nt] = __builtin_amdgcn_mfma_f32_16x16x32_bf16(pa, vb, oacc[nt], 0, 0, 0);
    }
  }

  // ---- pack O rows in own-wave LDS slice, 16B/lane store ----
  unsigned short* wb = Pm + w * 1152;
#pragma unroll
  for (int nt = 0; nt < 2; ++nt)
#pragma unroll
    for (int reg = 0; reg < 4; ++reg)
      wb[(lg * 4 + reg) * 40 + nt * 16 + lr] = f2b(oacc[nt][reg]);
  const int rr = lane >> 2, c8 = (lane & 3) * 8;
  const int row = w * 16 + rr;
  if (row < NTOK) {
    const ushort8 ov = *(const ushort8*)(wb + rr * 40 + c8);
    *(ushort8*)(attn_bf + ((size_t)(b * NTOK + row)) * 384 + h * 32 + c8) = ov;
  }
}

// ---------------------------------------------------------------------------
// proj GEMM: [120832][384] = attn_bf @ wproj_bf^T (+bias), f32 routed out.
// Now 1D grid + XCD swizzle (3 consecutive wg share the A row-tile).
// ---------------------------------------------------------------------------
__global__ __launch_bounds__(256) void gemm_proj_kernel(
    const unsigned short* __restrict__ A, const unsigned short* __restrict__ Bw,
    const float* __restrict__ b_proj, float* __restrict__ x_out,
    float* __restrict__ pbuf) {
  __shared__ unsigned short Asw[8192];
  __shared__ unsigned short Bsw[8192];
  const int t = threadIdx.x;
  const int w = t >> 6, lane = t & 63;
  const int lr = lane & 15, lg = lane >> 4;
  const int w0 = w >> 1, w1 = w & 1;
  const int wg = xcd_swz(blockIdx.x, 3 * 944);
  const size_t m0 = (size_t)(wg / 3) * 128;
  const int n0 = (wg % 3) * 128;
  const int srow = lane >> 3, cpos = lane & 7;

  floatx4 acc[4][4];
#pragma unroll
  for (int mr = 0; mr < 4; ++mr)
#pragma unroll
    for (int nc = 0; nc < 4; ++nc) acc[mr][nc] = (floatx4)0.f;

  for (int k0 = 0; k0 < 384; k0 += 64) {
#pragma unroll
    for (int i = 0; i < 4; ++i) {
      const int r = (w * 4 + i) * 8 + srow;
      const int c = cpos ^ (r & 7);
      gll16(A + (m0 + r) * 384 + k0 + c * 8, Asw + (w * 4 + i) * 512);
      gll16(Bw + (size_t)(n0 + r) * 384 + k0 + c * 8, Bsw + (w * 4 + i) * 512);
    }
    __syncthreads();
#pragma unroll
    for (int kh = 0; kh < 2; ++kh) {
      short8 af[4], bf[4];
#pragma unroll
      for (int mr = 0; mr < 4; ++mr) {
        const int r = w0 * 64 + mr * 16 + lr;
        af[mr] = *(const short8*)(Asw + r * 64 + (((kh * 4 + lg) ^ (r & 7)) * 8));
      }
#pragma unroll
      for (int nc = 0; nc < 4; ++nc) {
        const int r = w1 * 64 + nc * 16 + lr;
        bf[nc] = *(const short8*)(Bsw + r * 64 + (((kh * 4 + lg) ^ (r & 7)) * 8));
      }
#pragma unroll
      for (int mr = 0; mr < 4; ++mr)
#pragma unroll
        for (int nc = 0; nc < 4; ++nc)
          acc[mr][nc] = __builtin_amdgcn_mfma_f32_16x16x32_bf16(
              af[mr], bf[nc], acc[mr][nc], 0, 0, 0);
    }
    __syncthreads();
  }

  float bias[4]; int nn[4];
#pragma unroll
  for (int nc = 0; nc < 4; ++nc) {
    nn[nc] = n0 + w1 * 64 + nc * 16 + lr;
    bias[nc] = b_proj[nn[nc]];
  }
#pragma unroll
  for (int mr = 0; mr < 4; ++mr)
#pragma unroll
    for (int reg = 0; reg < 4; ++reg) {
      const int m = (int)m0 + w0 * 64 + mr * 16 + lg * 4 + reg;
      const int bb = m / 59, tok = m - bb * 59;
      float* dst = (tok >= P)
          ? x_out + (size_t)(bb * NWTOK + tok - P) * 384
          : pbuf + (size_t)(bb * P + tok) * 384;
#pragma unroll
      for (int nc = 0; nc < 4; ++nc)
        dst[nn[nc]] = acc[mr][nc][reg] + bias[nc];
    }
}

// ---------------------------------------------------------------------------
// prompts_out = mean over 64 windows
// ---------------------------------------------------------------------------
__global__ __launch_bounds__(256) void reduce_prompts_kernel(
    const float* __restrict__ pbuf, float* __restrict__ po) {
  const int o = blockIdx.x * 256 + threadIdx.x;  // < 32*10*384
  const int b0 = o / 3840;
  const int rem = o - b0 * 3840;
  const float* base = pbuf + (size_t)b0 * 64 * 3840 + rem;
  float s = 0.f;
#pragma unroll 8
  for (int w = 0; w < 64; ++w) s += base[(size_t)w * 3840];
  po[o] = s * (1.f / 64.f);
}

extern "C" void kernel_launch(void* const* d_in, const int* in_sizes, int n_in,
                              void* d_out, int out_size, void* d_ws, size_t ws_size,
                              hipStream_t stream) {
  const float* x          = (const float*)d_in[0];
  const float* spa        = (const float*)d_in[1];
  const float* mask       = (const float*)d_in[2];
  const float* bias_table = (const float*)d_in[3];
  const float* w_qkv      = (const float*)d_in[4];
  const float* b_qkv      = (const float*)d_in[5];
  const float* w_proj     = (const float*)d_in[6];
  const float* b_proj     = (const float*)d_in[7];
  float* out = (float*)d_out;

  // ws layout (bytes):
  // [0, 77070336)            x_bf  (bf16 100352x384)   } consumed by gemm_qkv,
  // [77070336, 77316096)     xp_bf (bf16 320x384)      } then region reused as
  // [77316096, 78200832)     wqkv_bf                   } attn_bf
  // [0, 92798976)            attn_bf (bf16 120832x384)
  // [92798976, 324009984)    qkx (bf16 [2048][3][49][384])
  // [324009984, 324747264)   qkp (bf16 [32][3][10][384])
  // [324747264, 325042176)   wproj_bf
  // [325042176, 356499456)   pbuf  (f32 2048*10*384)
  // [356499456, 369082368)   combo (f32 [64][12][64][64])
  unsigned short* x_bf     = (unsigned short*)d_ws;
  unsigned short* attn_bf  = (unsigned short*)d_ws;
  unsigned short* xp_bf    = (unsigned short*)((char*)d_ws + 77070336ULL);
  unsigned short* wqkv_bf  = (unsigned short*)((char*)d_ws + 77316096ULL);
  unsigned short* qkx      = (unsigned short*)((char*)d_ws + 92798976ULL);
  unsigned short* qkp      = (unsigned short*)((char*)d_ws + 324009984ULL);
  unsigned short* wproj_bf = (unsigned short*)((char*)d_ws + 324747264ULL);
  float*          pbuf     = (float*)((char*)d_ws + 325042176ULL);
  float*          combo    = (float*)((char*)d_ws + 356499456ULL);

  convert_w_kernel<<<18816, 256, 0, stream>>>(x, x_bf);
  convert_w_kernel<<<60, 256, 0, stream>>>(spa, xp_bf);
  convert_w_kernel<<<216, 256, 0, stream>>>(w_qkv, wqkv_bf);
  convert_w_kernel<<<72, 256, 0, stream>>>(w_proj, wproj_bf);
  combo_kernel<<<768, 256, 0, stream>>>(mask, bias_table, combo);
  gemm_qkv_kernel<<<9 * 787, 256, 0, stream>>>(x_bf, xp_bf, wqkv_bf, b_qkv,
                                               qkx, qkp);
  attn_kernel<<<2048 * HEADS, 256, 0, stream>>>(qkx, qkp, combo, out + AW_OFF,
                                                attn_bf);
  gemm_proj_kernel<<<3 * 944, 256, 0, stream>>>(attn_bf, wproj_bf, b_proj,
                                                out, pbuf);
  reduce_prompts_kernel<<<480, 256, 0, stream>>>(pbuf, out + PO_OFF);
}